// Round 1
// baseline (236.178 us; speedup 1.0000x reference)
//
#include <hip/hip_runtime.h>
#include <hip/hip_bf16.h>
#include <stdint.h>

#define DIM 256
#define GRID_G 5
#define KTOT (DIM * GRID_G * 2)   // 2560
#define BM 128
#define BN 256
#define BK 64
#define NTHREADS 512

typedef float f32x4 __attribute__((ext_vector_type(4)));
typedef short bf16x8 __attribute__((ext_vector_type(8)));

// ---- helpers ----
static __device__ __forceinline__ uint32_t f2bf_bits(float v) {
    // round-to-nearest-even bf16 (inputs are finite trig values / weights)
    uint32_t u = __float_as_uint(v);
    return (u + 0x7FFFu + ((u >> 16) & 1u)) >> 16;
}

static __device__ __forceinline__ void gload_lds16(const void* g, void* l) {
    __builtin_amdgcn_global_load_lds(
        (const __attribute__((address_space(1))) void*)g,
        (__attribute__((address_space(3))) void*)l, 16, 0, 0);
}

// ---- W pre-transform: Wb[o][k] bf16, k = g*512 + 2*d + s ----
// fourier_weight layout: [s][o][d][g], flat ((s*256+o)*256+d)*5+g
__global__ void wtransform(const float* __restrict__ W, uint16_t* __restrict__ Wb) {
    int idx = blockIdx.x * blockDim.x + threadIdx.x;
    if (idx >= DIM * KTOT) return;
    int o = idx / KTOT;
    int k = idx - o * KTOT;
    int g = k >> 9;          // k / 512
    int r = k & 511;
    int d = r >> 1;
    int s = r & 1;
    float w = W[(((s * DIM + o) * DIM + d) * GRID_G) + g];
    Wb[idx] = (uint16_t)f2bf_bits(w);
}

// ---- fused feature+GEMM ----
// A (features) tile: As[n][klocal], 128 rows x 64 k x 2B = 128B/row, XOR-swizzled
// B (weights) tile:  Bs[o][klocal], 256 rows x 64 k x 2B = 128B/row, XOR-swizzled
__global__ __launch_bounds__(NTHREADS, 4)
void fourier_gemm(const float* __restrict__ x, const uint16_t* __restrict__ Wb,
                  const float* __restrict__ bias, float* __restrict__ out) {
    __shared__ __align__(16) short As[BM * BK];   // 16 KB
    __shared__ __align__(16) short Bs[BN * BK];   // 32 KB

    const int tid  = threadIdx.x;
    const int lane = tid & 63;
    const int wave = tid >> 6;
    const int wrow = wave >> 2;    // 0..1  (rows of 64)
    const int wcol = wave & 3;     // 0..3  (cols of 64)
    const int row0 = blockIdx.x * BM;

    f32x4 acc[4][4];
#pragma unroll
    for (int m = 0; m < 4; ++m)
#pragma unroll
        for (int n = 0; n < 4; ++n)
            acc[m][n] = (f32x4){0.f, 0.f, 0.f, 0.f};

    const int sd = tid & 31;       // d-offset within 32 for staging
    const int sn = tid >> 5;       // base row 0..15 for staging

    const int q16 = (lane >> 4) << 4;   // 16-byte k-group offset for frag reads

    for (int c = 0; c < KTOT / BK; ++c) {   // 40 chunks
        const int g  = c >> 3;              // harmonic index 0..4
        const int d0 = (c & 7) * 32;        // d-range base
        const float kg = (float)(g + 1);

        // ---- stage B: global_load_lds, linear LDS dest + pre-swizzled global src
        {
            const char* wbb = (const char*)Wb + (size_t)c * 128;  // k-offset bytes
#pragma unroll
            for (int i = 0; i < 4; ++i) {
                int f   = tid * 16 + i * 8192;          // flat byte offset in 32KB tile
                int o   = f >> 7;                       // LDS row (= output col)
                int col = f & 127;
                int scol = col ^ ((o & 7) << 4);        // inverse swizzle on source
                gload_lds16(wbb + (size_t)o * (KTOT * 2) + scol, (char*)Bs + f);
            }
        }

        // ---- stage A: compute cos/sin features, swizzled b32 writes
        {
#pragma unroll
            for (int i = 0; i < 8; ++i) {
                int n = sn + i * 16;
                float xv = x[(size_t)(row0 + n) * DIM + (d0 + sd)];
                float a  = kg * xv;
                float sv = __sinf(a);
                float cv = __cosf(a);
                uint32_t pk = (f2bf_bits(sv) << 16) | f2bf_bits(cv);  // cos at k=2d, sin at 2d+1
                int boff = (n * 128 + sd * 4) ^ ((n & 7) << 4);
                *(uint32_t*)((char*)As + boff) = pk;
            }
        }

        __syncthreads();

        // ---- MFMA phase: 2 k-steps x (4x4) fragments
#pragma unroll
        for (int ks = 0; ks < 2; ++ks) {
            bf16x8 af[4], bfr[4];
#pragma unroll
            for (int m = 0; m < 4; ++m) {
                int r = wrow * 64 + m * 16 + (lane & 15);
                int off = (r * 128 + ks * 64 + q16) ^ ((r & 7) << 4);
                af[m] = *(const bf16x8*)((const char*)As + off);
            }
#pragma unroll
            for (int nf = 0; nf < 4; ++nf) {
                int o = wcol * 64 + nf * 16 + (lane & 15);
                int off = (o * 128 + ks * 64 + q16) ^ ((o & 7) << 4);
                bfr[nf] = *(const bf16x8*)((const char*)Bs + off);
            }
#pragma unroll
            for (int m = 0; m < 4; ++m)
#pragma unroll
                for (int nf = 0; nf < 4; ++nf)
                    acc[m][nf] = __builtin_amdgcn_mfma_f32_16x16x32_bf16(
                        af[m], bfr[nf], acc[m][nf], 0, 0, 0);
        }

        __syncthreads();
    }

    // ---- epilogue: C/D layout col = lane&15, row = (lane>>4)*4 + reg
#pragma unroll
    for (int m = 0; m < 4; ++m) {
        int rbase = row0 + wrow * 64 + m * 16 + ((lane >> 4) << 2);
#pragma unroll
        for (int nf = 0; nf < 4; ++nf) {
            int ocol = wcol * 64 + nf * 16 + (lane & 15);
            float b = bias[ocol];
#pragma unroll
            for (int r = 0; r < 4; ++r) {
                out[(size_t)(rbase + r) * DIM + ocol] = acc[m][nf][r] + b;
            }
        }
    }
}

extern "C" void kernel_launch(void* const* d_in, const int* in_sizes, int n_in,
                              void* d_out, int out_size, void* d_ws, size_t ws_size,
                              hipStream_t stream) {
    const float* x    = (const float*)d_in[0];
    const float* W    = (const float*)d_in[1];
    const float* bias = (const float*)d_in[2];
    float* out        = (float*)d_out;
    uint16_t* Wb      = (uint16_t*)d_ws;   // 256*2560*2 = 1.28 MB

    int rows = in_sizes[0] / DIM;          // 65536
    int wtot = DIM * KTOT;                 // 655360

    hipLaunchKernelGGL(wtransform, dim3((wtot + 255) / 256), dim3(256), 0, stream, W, Wb);
    hipLaunchKernelGGL(fourier_gemm, dim3(rows / BM), dim3(NTHREADS), 0, stream,
                       x, Wb, bias, out);
}

// Round 2
// 200.469 us; speedup vs baseline: 1.1781x; 1.1781x over previous
//
#include <hip/hip_runtime.h>
#include <hip/hip_bf16.h>
#include <stdint.h>

#define DIM 256
#define GRID_G 5
#define KTOT (DIM * GRID_G * 2)   // 2560
#define BM 256
#define BN 256
#define BK 64
#define NTHREADS 512
#define NCHUNK (KTOT / BK)        // 40
#define AS_SH (BM * BK)           // 16384 shorts = 32 KB
#define BS_SH (BN * BK)           // 16384 shorts = 32 KB

typedef float f32x4 __attribute__((ext_vector_type(4)));
typedef short bf16x8 __attribute__((ext_vector_type(8)));

static __device__ __forceinline__ uint32_t f2bf_bits(float v) {
    uint32_t u = __float_as_uint(v);
    return (u + 0x7FFFu + ((u >> 16) & 1u)) >> 16;
}

static __device__ __forceinline__ void gload_lds16(const void* g, void* l) {
    __builtin_amdgcn_global_load_lds(
        (const __attribute__((address_space(1))) void*)g,
        (__attribute__((address_space(3))) void*)l, 16, 0, 0);
}

// ---- W pre-transform: Wb[o][k] bf16, k = g*512 + 2*d + s ----
// fourier_weight layout: [s][o][d][g], flat ((s*256+o)*256+d)*5+g
__global__ void wtransform(const float* __restrict__ W, uint16_t* __restrict__ Wb) {
    int idx = blockIdx.x * blockDim.x + threadIdx.x;
    if (idx >= DIM * KTOT) return;
    int o = idx / KTOT;
    int k = idx - o * KTOT;
    int g = k >> 9;
    int r = k & 511;
    int d = r >> 1;
    int s = r & 1;
    float w = W[(((s * DIM + o) * DIM + d) * GRID_G) + g];
    Wb[idx] = (uint16_t)f2bf_bits(w);
}

// ---- fused feature+GEMM, BM=256 x BN=256, double-buffered, 1 barrier/chunk ----
__global__ __launch_bounds__(NTHREADS, 2)
void fourier_gemm(const float* __restrict__ x, const uint16_t* __restrict__ Wb,
                  const float* __restrict__ bias, float* __restrict__ out) {
    __shared__ __align__(16) short As[2 * AS_SH];   // 64 KB
    __shared__ __align__(16) short Bs[2 * BS_SH];   // 64 KB

    const int tid  = threadIdx.x;
    const int lane = tid & 63;
    const int wave = tid >> 6;
    const int wrow = wave >> 2;    // 0..1  (128-row halves)
    const int wcol = wave & 3;     // 0..3  (64-col quarters)
    const int row0 = blockIdx.x * BM;
    const int q16  = (lane >> 4) << 4;

    f32x4 acc[8][4];
#pragma unroll
    for (int m = 0; m < 8; ++m)
#pragma unroll
        for (int n = 0; n < 4; ++n)
            acc[m][n] = (f32x4){0.f, 0.f, 0.f, 0.f};

    const int sd2 = tid & 15;      // d-pair index (dlocal 2*sd2, 2*sd2+1)
    const int sn  = tid >> 4;      // 0..31 (row base)

    float2 xq[8];                  // prefetched x for the chunk being staged

#define STAGE_B(cc, buf)                                                      \
    {                                                                         \
        const char* wbb = (const char*)Wb + (size_t)(cc) * 128;               \
        char* dst = (char*)(Bs + (buf) * BS_SH);                              \
        _Pragma("unroll")                                                     \
        for (int i = 0; i < 4; ++i) {                                         \
            int f = tid * 16 + i * 8192;                                      \
            int o = f >> 7;                                                   \
            int col = f & 127;                                                \
            int scol = col ^ ((o & 7) << 4);                                  \
            gload_lds16(wbb + (size_t)o * (KTOT * 2) + scol, dst + f);        \
        }                                                                     \
    }

#define LOAD_X(cc)                                                            \
    {                                                                         \
        int d0 = ((cc) & 7) * 32;                                             \
        _Pragma("unroll")                                                     \
        for (int i = 0; i < 8; ++i) {                                         \
            int n = sn + i * 32;                                              \
            xq[i] = *(const float2*)&x[(size_t)(row0 + n) * DIM + d0 + 2 * sd2]; \
        }                                                                     \
    }

#define TRIG_WRITE(cc, buf)                                                   \
    {                                                                         \
        float kgrev = (float)(((cc) >> 3) + 1) * 0.15915494309189535f;        \
        char* abase = (char*)(As + (buf) * AS_SH);                            \
        _Pragma("unroll")                                                     \
        for (int i = 0; i < 8; ++i) {                                         \
            int n = sn + i * 32;                                              \
            float r0 = xq[i].x * kgrev;                                       \
            float r1 = xq[i].y * kgrev;                                       \
            float s0, c0, s1, c1;                                             \
            asm("v_sin_f32 %0, %1" : "=v"(s0) : "v"(r0));                     \
            asm("v_cos_f32 %0, %1" : "=v"(c0) : "v"(r0));                     \
            asm("v_sin_f32 %0, %1" : "=v"(s1) : "v"(r1));                     \
            asm("v_cos_f32 %0, %1" : "=v"(c1) : "v"(r1));                     \
            uint32_t p0, p1;                                                  \
            asm("v_cvt_pk_bf16_f32 %0, %1, %2" : "=v"(p0) : "v"(c0), "v"(s0));\
            asm("v_cvt_pk_bf16_f32 %0, %1, %2" : "=v"(p1) : "v"(c1), "v"(s1));\
            int boff = (n * 128 + sd2 * 8) ^ ((n & 7) << 4);                  \
            uint64_t pk = ((uint64_t)p1 << 32) | (uint64_t)p0;                \
            *(uint64_t*)(abase + boff) = pk;                                  \
        }                                                                     \
    }

    // ---- prologue: stage chunk 0 into buffer 0
    STAGE_B(0, 0);
    LOAD_X(0);
    TRIG_WRITE(0, 0);
    __syncthreads();

    for (int c = 0; c < NCHUNK; ++c) {
        const int cur = c & 1;
        const int nxt = cur ^ 1;

        // issue next chunk's B loads + x loads early (latency hides under MFMA)
        if (c + 1 < NCHUNK) {
            STAGE_B(c + 1, nxt);
            LOAD_X(c + 1);
        }

        const char* Ac = (const char*)(As + cur * AS_SH);
        const char* Bc = (const char*)(Bs + cur * BS_SH);

#pragma unroll
        for (int ks = 0; ks < 2; ++ks) {
            bf16x8 af[8], bfr[4];
#pragma unroll
            for (int m = 0; m < 8; ++m) {
                int r = wrow * 128 + m * 16 + (lane & 15);
                int off = (r * 128 + ks * 64 + q16) ^ ((r & 7) << 4);
                af[m] = *(const bf16x8*)(Ac + off);
            }
#pragma unroll
            for (int nf = 0; nf < 4; ++nf) {
                int o = wcol * 64 + nf * 16 + (lane & 15);
                int off = (o * 128 + ks * 64 + q16) ^ ((o & 7) << 4);
                bfr[nf] = *(const bf16x8*)(Bc + off);
            }
#pragma unroll
            for (int m = 0; m < 8; ++m)
#pragma unroll
                for (int nf = 0; nf < 4; ++nf)
                    acc[m][nf] = __builtin_amdgcn_mfma_f32_16x16x32_bf16(
                        af[m], bfr[nf], acc[m][nf], 0, 0, 0);
        }

        // trig + LDS write for next chunk (opposite buffer → no extra barrier)
        if (c + 1 < NCHUNK) {
            TRIG_WRITE(c + 1, nxt);
        }

        __syncthreads();
    }

    // ---- epilogue: C/D layout col = lane&15, row = (lane>>4)*4 + reg
#pragma unroll
    for (int nf = 0; nf < 4; ++nf) {
        int ocol = wcol * 64 + nf * 16 + (lane & 15);
        float b = bias[ocol];
#pragma unroll
        for (int m = 0; m < 8; ++m) {
            int rbase = row0 + wrow * 128 + m * 16 + ((lane >> 4) << 2);
#pragma unroll
            for (int r = 0; r < 4; ++r) {
                out[(size_t)(rbase + r) * DIM + ocol] = acc[m][nf][r] + b;
            }
        }
    }
}

extern "C" void kernel_launch(void* const* d_in, const int* in_sizes, int n_in,
                              void* d_out, int out_size, void* d_ws, size_t ws_size,
                              hipStream_t stream) {
    const float* x    = (const float*)d_in[0];
    const float* W    = (const float*)d_in[1];
    const float* bias = (const float*)d_in[2];
    float* out        = (float*)d_out;
    uint16_t* Wb      = (uint16_t*)d_ws;   // 256*2560*2 = 1.28 MB

    int rows = in_sizes[0] / DIM;          // 65536
    int wtot = DIM * KTOT;                 // 655360

    hipLaunchKernelGGL(wtransform, dim3((wtot + 255) / 256), dim3(256), 0, stream, W, Wb);
    hipLaunchKernelGGL(fourier_gemm, dim3(rows / BM), dim3(NTHREADS), 0, stream,
                       x, Wb, bias, out);
}